// Round 1
// baseline (1614.600 us; speedup 1.0000x reference)
//
#include <hip/hip_runtime.h>

// PixelPropagationModule: out = gamma * (softmax(q k^T) @ v^T)^T + x
// B=8, C=256, CI=64, H=W=56, N=3136. All fp32.
// Round 0: correctness-first fp32 flash-attention structure.
//   proj_kernel: q[B][N][CI], k[B][CI][N], v[B][N][C] into workspace
//   attn_kernel: TQ=64 queries/block, TJ=64 key tile, online softmax,
//                lane owns 4 channels (float4 v loads), O[16][4] in regs.

constexpr int B_  = 8;
constexpr int C_  = 256;
constexpr int CI_ = 64;
constexpr int N_  = 3136;   // 56*56
constexpr int PT  = 32;     // proj pixel tile
constexpr int TQ  = 64;     // query tile per block
constexpr int TJ  = 64;     // key tile

__global__ __launch_bounds__(256)
void proj_kernel(const float* __restrict__ x,
                 const float* __restrict__ Wq, const float* __restrict__ bq,
                 const float* __restrict__ Wk, const float* __restrict__ bk,
                 const float* __restrict__ Wv, const float* __restrict__ bv,
                 float* __restrict__ qb, float* __restrict__ kb, float* __restrict__ vb)
{
    __shared__ float xs[C_][PT];                 // 32 KB
    const int bpb = N_ / PT;                     // 98
    const int b   = blockIdx.x / bpb;
    const int n0  = (blockIdx.x % bpb) * PT;
    const int tid = threadIdx.x;

    // stage x tile (coalesced over n)
    #pragma unroll
    for (int rep = 0; rep < C_ * PT / 256; rep++) {
        int e  = rep * 256 + tid;
        int cc = e >> 5, nn = e & 31;
        xs[cc][nn] = x[((size_t)b * C_ + cc) * N_ + n0 + nn];
    }
    __syncthreads();

    // V: thread = output channel (256 threads = 256 channels)
    {
        float bias = bv[tid];
        float acc[PT];
        #pragma unroll
        for (int i = 0; i < PT; i++) acc[i] = bias;
        for (int ch = 0; ch < C_; ch++) {
            float w = Wv[(size_t)tid * C_ + ch];
            #pragma unroll
            for (int nn = 0; nn < PT; nn++) acc[nn] += w * xs[ch][nn];
        }
        #pragma unroll
        for (int nn = 0; nn < PT; nn++)
            vb[((size_t)b * N_ + n0 + nn) * C_ + tid] = acc[nn];   // [B][N][C]
    }

    // Q, K: o = tid&63, 8 pixels per thread
    {
        int o  = tid & 63;
        int ns = (tid >> 6) * 8;
        float aq[8], ak[8];
        float bq_ = bq[o], bk_ = bk[o];
        #pragma unroll
        for (int i = 0; i < 8; i++) { aq[i] = bq_; ak[i] = bk_; }
        for (int ch = 0; ch < C_; ch++) {
            float wq = Wq[(size_t)o * C_ + ch];
            float wk = Wk[(size_t)o * C_ + ch];
            #pragma unroll
            for (int i = 0; i < 8; i++) {
                float xv = xs[ch][ns + i];
                aq[i] += wq * xv;
                ak[i] += wk * xv;
            }
        }
        #pragma unroll
        for (int i = 0; i < 8; i++) {
            qb[((size_t)b * N_ + n0 + ns + i) * CI_ + o] = aq[i];  // [B][N][CI]
            kb[((size_t)b * CI_ + o) * N_ + n0 + ns + i] = ak[i];  // [B][CI][N]
        }
    }
}

__global__ __launch_bounds__(256)
void attn_kernel(const float* __restrict__ qb, const float* __restrict__ kb,
                 const float* __restrict__ vb, const float* __restrict__ x,
                 const float* __restrict__ gamma_p, float* __restrict__ out)
{
    __shared__ float qs[TQ][CI_];       // 16 KB
    __shared__ float ks[CI_][TJ];       // 16 KB (o-major: conflict-free lane reads)
    __shared__ float ps[TQ][TJ + 4];    // 17 KB (pad keeps 16B row alignment, kills conflicts)
    __shared__ float mstat[TQ], lstat[TQ], alpha_s[TQ];

    const int bpb  = N_ / TQ;            // 49
    const int b    = blockIdx.x / bpb;
    const int i0   = (blockIdx.x % bpb) * TQ;
    const int tid  = threadIdx.x;
    const int g    = tid >> 6;           // wave id = query group
    const int lane = tid & 63;
    const int cbase = lane * 4;          // this lane's 4 channels

    // load q tile
    for (int e = tid; e < TQ * CI_; e += 256) {
        int qq = e >> 6, o = e & 63;
        qs[qq][o] = qb[((size_t)b * N_ + i0 + qq) * CI_ + o];
    }
    if (tid < TQ) { mstat[tid] = -3.0e38f; lstat[tid] = 0.f; }

    float O[16][4];
    #pragma unroll
    for (int i = 0; i < 16; i++)
        #pragma unroll
        for (int c4 = 0; c4 < 4; c4++) O[i][c4] = 0.f;

    for (int j0 = 0; j0 < N_; j0 += TJ) {
        __syncthreads();
        // stage k tile: ks[o][jj]  (global coalesced over jj)
        for (int e = tid; e < CI_ * TJ; e += 256) {
            int o = e >> 6, jj = e & 63;
            ks[o][jj] = kb[((size_t)b * CI_ + o) * N_ + j0 + jj];
        }
        __syncthreads();

        // scores: thread -> column jj = lane, rows g*16..g*16+15
        {
            float s[16];
            #pragma unroll
            for (int i = 0; i < 16; i++) s[i] = 0.f;
            #pragma unroll
            for (int o4 = 0; o4 < CI_; o4 += 4) {
                float k0 = ks[o4 + 0][lane];
                float k1 = ks[o4 + 1][lane];
                float k2 = ks[o4 + 2][lane];
                float k3 = ks[o4 + 3][lane];
                #pragma unroll
                for (int i = 0; i < 16; i++) {
                    const float4 q4 = *(const float4*)&qs[g * 16 + i][o4];
                    s[i] += q4.x * k0 + q4.y * k1 + q4.z * k2 + q4.w * k3;
                }
            }
            #pragma unroll
            for (int i = 0; i < 16; i++) ps[g * 16 + i][lane] = s[i];
        }
        __syncthreads();

        // online-softmax stats: each wave handles its own 16 rows, 4 lanes/row
        {
            int row  = g * 16 + (lane >> 2);
            int part = lane & 3;
            float* pr = &ps[row][part * 16];
            float m_new = -3.0e38f;
            #pragma unroll
            for (int u = 0; u < 16; u++) m_new = fmaxf(m_new, pr[u]);
            m_new = fmaxf(m_new, __shfl_xor(m_new, 1));
            m_new = fmaxf(m_new, __shfl_xor(m_new, 2));
            float m_old = mstat[row];
            float m_tot = fmaxf(m_old, m_new);
            float lsum = 0.f;
            #pragma unroll
            for (int u = 0; u < 16; u++) {
                float p = __expf(pr[u] - m_tot);
                pr[u] = p;
                lsum += p;
            }
            lsum += __shfl_xor(lsum, 1);
            lsum += __shfl_xor(lsum, 2);
            if (part == 0) {
                alpha_s[row] = __expf(m_old - m_tot);
                lstat[row]   = lstat[row] * __expf(m_old - m_tot) + lsum;
                mstat[row]   = m_tot;
            }
        }
        __syncthreads();

        // accumulate O += P * V  (lane owns 4 channels; ps reads are wave-broadcast)
        {
            #pragma unroll
            for (int i = 0; i < 16; i++) {
                float a = alpha_s[g * 16 + i];
                #pragma unroll
                for (int c4 = 0; c4 < 4; c4++) O[i][c4] *= a;
            }
            const float* vbase = vb + ((size_t)b * N_ + j0) * C_ + cbase;
            #pragma unroll 4
            for (int jj4 = 0; jj4 < TJ; jj4 += 4) {
                float4 vv0 = *(const float4*)(vbase + (size_t)(jj4 + 0) * C_);
                float4 vv1 = *(const float4*)(vbase + (size_t)(jj4 + 1) * C_);
                float4 vv2 = *(const float4*)(vbase + (size_t)(jj4 + 2) * C_);
                float4 vv3 = *(const float4*)(vbase + (size_t)(jj4 + 3) * C_);
                #pragma unroll
                for (int i = 0; i < 16; i++) {
                    const float4 p4 = *(const float4*)&ps[g * 16 + i][jj4];
                    O[i][0] += p4.x * vv0.x + p4.y * vv1.x + p4.z * vv2.x + p4.w * vv3.x;
                    O[i][1] += p4.x * vv0.y + p4.y * vv1.y + p4.z * vv2.y + p4.w * vv3.y;
                    O[i][2] += p4.x * vv0.z + p4.y * vv1.z + p4.z * vv2.z + p4.w * vv3.z;
                    O[i][3] += p4.x * vv0.w + p4.y * vv1.w + p4.z * vv2.w + p4.w * vv3.w;
                }
            }
        }
    }
    __syncthreads();

    // epilogue: out[b][c][i] = gamma * O/l + x   (float4 along N)
    float inv_l[16];
    #pragma unroll
    for (int i = 0; i < 16; i++) inv_l[i] = 1.0f / lstat[g * 16 + i];
    const float gmm = gamma_p[0];
    #pragma unroll
    for (int c4 = 0; c4 < 4; c4++) {
        const size_t rowoff = ((size_t)b * C_ + cbase + c4) * N_ + i0 + g * 16;
        #pragma unroll
        for (int i4 = 0; i4 < 4; i4++) {
            float4 xv = *(const float4*)(x + rowoff + i4 * 4);
            float4 ov;
            ov.x = gmm * O[i4 * 4 + 0][c4] * inv_l[i4 * 4 + 0] + xv.x;
            ov.y = gmm * O[i4 * 4 + 1][c4] * inv_l[i4 * 4 + 1] + xv.y;
            ov.z = gmm * O[i4 * 4 + 2][c4] * inv_l[i4 * 4 + 2] + xv.z;
            ov.w = gmm * O[i4 * 4 + 3][c4] * inv_l[i4 * 4 + 3] + xv.w;
            *(float4*)(out + rowoff + i4 * 4) = ov;
        }
    }
}

extern "C" void kernel_launch(void* const* d_in, const int* in_sizes, int n_in,
                              void* d_out, int out_size, void* d_ws, size_t ws_size,
                              hipStream_t stream)
{
    const float* x  = (const float*)d_in[0];
    const float* Wq = (const float*)d_in[1];
    const float* bq = (const float*)d_in[2];
    const float* Wk = (const float*)d_in[3];
    const float* bk = (const float*)d_in[4];
    const float* Wv = (const float*)d_in[5];
    const float* bv = (const float*)d_in[6];
    const float* gm = (const float*)d_in[7];
    float* out = (float*)d_out;

    float* qb = (float*)d_ws;                       // [B][N][CI]  6.4 MB
    float* kb = qb + (size_t)B_ * N_ * CI_;         // [B][CI][N]  6.4 MB
    float* vb = kb + (size_t)B_ * N_ * CI_;         // [B][N][C]  25.7 MB

    hipLaunchKernelGGL(proj_kernel, dim3(B_ * (N_ / PT)), dim3(256), 0, stream,
                       x, Wq, bq, Wk, bk, Wv, bv, qb, kb, vb);
    hipLaunchKernelGGL(attn_kernel, dim3(B_ * (N_ / TQ)), dim3(256), 0, stream,
                       qb, kb, vb, x, gm, out);
}

// Round 2
// 592.596 us; speedup vs baseline: 2.7246x; 2.7246x over previous
//
#include <hip/hip_runtime.h>

// PixelPropagationModule  out = gamma * (softmax(qk^T) @ v^T)^T + x
// B=8, C=256, CI=64, N=3136 (56x56), fp32 in/out.
// R1: bf16 MFMA flash attention.
//   proj_kernel (fp32 VALU): q[B][N][CI] bf16, k[B][N][CI] bf16, vT[B][C][N] bf16
//   attn_kernel: TQ=32 q/block, TJ=64 k/step, 4 waves.
//     QK^T: mfma_f32_16x16x32_bf16, wave w = j-tile w; S -> LDS (C-layout).
//     online softmax fp32 in LDS (8 lanes/row), P -> bf16 LDS (pad +8).
//     PV: wave w = 64 channels (4 c-tiles), P A-frags via LDS, V frags from global.

constexpr int B_  = 8;
constexpr int C_  = 256;
constexpr int CI_ = 64;
constexpr int N_  = 3136;
constexpr int PT  = 32;     // proj pixel tile
constexpr int TQ  = 32;     // query tile per block
constexpr int TJ  = 64;     // key tile per step

typedef __attribute__((ext_vector_type(8))) short short8;   // 8 bf16 (4 VGPR)
typedef __attribute__((ext_vector_type(4))) float f32x4;

static __device__ inline ushort f2b(float f) {               // fp32 -> bf16 (RNE)
    unsigned u = __float_as_uint(f);
    return (ushort)((u + 0x7fffu + ((u >> 16) & 1u)) >> 16);
}

__global__ __launch_bounds__(256)
void proj_kernel(const float* __restrict__ x,
                 const float* __restrict__ Wq, const float* __restrict__ bq,
                 const float* __restrict__ Wk, const float* __restrict__ bk,
                 const float* __restrict__ Wv, const float* __restrict__ bv,
                 ushort* __restrict__ qb, ushort* __restrict__ kb, ushort* __restrict__ vt)
{
    __shared__ float xs[C_][PT];                 // 32 KB
    const int bpb = N_ / PT;                     // 98
    const int b   = blockIdx.x / bpb;
    const int n0  = (blockIdx.x % bpb) * PT;
    const int tid = threadIdx.x;

    #pragma unroll
    for (int rep = 0; rep < C_ * PT / 256; rep++) {
        int e  = rep * 256 + tid;
        int cc = e >> 5, nn = e & 31;
        xs[cc][nn] = x[((size_t)b * C_ + cc) * N_ + n0 + nn];
    }
    __syncthreads();

    // Q, K: thread o = tid&63, 8 pixels each; stores are 128B-contiguous per wave
    {
        int o  = tid & 63;
        int ns = (tid >> 6) * 8;
        float aq[8], ak[8];
        float bq_ = bq[o], bk_ = bk[o];
        #pragma unroll
        for (int i = 0; i < 8; i++) { aq[i] = bq_; ak[i] = bk_; }
        for (int ch = 0; ch < C_; ch++) {
            float wq = Wq[(size_t)o * C_ + ch];
            float wk = Wk[(size_t)o * C_ + ch];
            #pragma unroll
            for (int i = 0; i < 8; i++) {
                float xv = xs[ch][ns + i];
                aq[i] += wq * xv;
                ak[i] += wk * xv;
            }
        }
        #pragma unroll
        for (int i = 0; i < 8; i++) {
            qb[((size_t)b * N_ + n0 + ns + i) * CI_ + o] = f2b(aq[i]);  // [B][N][CI]
            kb[((size_t)b * N_ + n0 + ns + i) * CI_ + o] = f2b(ak[i]);  // [B][N][CI]
        }
    }

    // V: thread -> pixel nn = tid&31, channel group (tid>>5)*32 .. +31
    // stores land as 2 rows x 64B contiguous per wave instruction
    {
        int nn = tid & 31;
        int c0 = (tid >> 5) * 32;
        #pragma unroll 4
        for (int cc = 0; cc < 32; cc++) {
            int c = c0 + cc;
            float acc = bv[c];
            const float* wr = &Wv[(size_t)c * C_];
            for (int ch = 0; ch < C_; ch++) acc += wr[ch] * xs[ch][nn];
            vt[((size_t)b * C_ + c) * N_ + n0 + nn] = f2b(acc);         // [B][C][N]
        }
    }
}

__global__ __launch_bounds__(256)
void attn_kernel(const ushort* __restrict__ qb, const ushort* __restrict__ kb,
                 const ushort* __restrict__ vt, const float* __restrict__ x,
                 const float* __restrict__ gamma_p, float* __restrict__ out)
{
    __shared__ float  ps[TQ][TJ + 4];     // fp32 scores, 8704 B
    __shared__ ushort psb[TQ][TJ + 8];    // bf16 P, pad+8 keeps 16B align & spreads banks
    __shared__ float  mstat[TQ], lstat[TQ], alpha_s[TQ];

    const int bpb  = N_ / TQ;             // 98 -> grid 784
    const int b    = blockIdx.x / bpb;
    const int i0   = (blockIdx.x % bpb) * TQ;
    const int tid  = threadIdx.x;
    const int w    = tid >> 6;            // wave: QK j-tile, PV channel chunk
    const int lane = tid & 63;
    const int m16  = lane & 15;
    const int quad = lane >> 4;

    // Q A-frags, loaded once: qf[it][ko], A[m=i][k=o] = q[i][o]
    short8 qf[2][2];
    {
        const ushort* qbase = qb + ((size_t)b * N_ + i0) * CI_;
        #pragma unroll
        for (int it = 0; it < 2; it++)
            #pragma unroll
            for (int ko = 0; ko < 2; ko++)
                qf[it][ko] = *(const short8*)(qbase + (size_t)(it * 16 + m16) * CI_ + ko * 32 + quad * 8);
    }

    if (tid < TQ) { mstat[tid] = -3.0e38f; lstat[tid] = 0.f; }

    f32x4 O[2][4];                        // [it][ct] PV accumulators
    #pragma unroll
    for (int it = 0; it < 2; it++)
        #pragma unroll
        for (int ct = 0; ct < 4; ct++) O[it][ct] = (f32x4){0.f, 0.f, 0.f, 0.f};

    const ushort* kbbase = kb + (size_t)b * N_ * CI_;
    const ushort* vbase  = vt + ((size_t)b * C_ + w * 64) * N_;

    for (int j0 = 0; j0 < N_; j0 += TJ) {
        // ---- QK^T: wave w computes S[0:32][w*16 : w*16+16] ----
        {
            short8 kf[2];   // B[k=o][n=j] = k[j][o]
            #pragma unroll
            for (int ko = 0; ko < 2; ko++)
                kf[ko] = *(const short8*)(kbbase + (size_t)(j0 + w * 16 + m16) * CI_ + ko * 32 + quad * 8);
            #pragma unroll
            for (int it = 0; it < 2; it++) {
                f32x4 s = (f32x4){0.f, 0.f, 0.f, 0.f};
                s = __builtin_amdgcn_mfma_f32_16x16x32_bf16(qf[it][0], kf[0], s, 0, 0, 0);
                s = __builtin_amdgcn_mfma_f32_16x16x32_bf16(qf[it][1], kf[1], s, 0, 0, 0);
                #pragma unroll
                for (int r = 0; r < 4; r++)
                    ps[it * 16 + quad * 4 + r][w * 16 + m16] = s[r];
            }
        }
        __syncthreads();

        // ---- online softmax: 8 lanes per row (row = tid>>3) ----
        {
            int row  = tid >> 3;
            int part = tid & 7;
            float* pr = &ps[row][part * 8];
            float mnew = -3.0e38f;
            #pragma unroll
            for (int u = 0; u < 8; u++) mnew = fmaxf(mnew, pr[u]);
            mnew = fmaxf(mnew, __shfl_xor(mnew, 1));
            mnew = fmaxf(mnew, __shfl_xor(mnew, 2));
            mnew = fmaxf(mnew, __shfl_xor(mnew, 4));
            float mold = mstat[row];                 // same-wave lockstep: read before write below
            float mtot = fmaxf(mold, mnew);
            float lsum = 0.f;
            ushort* pb = &psb[row][part * 8];
            #pragma unroll
            for (int u = 0; u < 8; u++) {
                float p = __expf(pr[u] - mtot);
                pb[u] = f2b(p);
                lsum += p;
            }
            lsum += __shfl_xor(lsum, 1);
            lsum += __shfl_xor(lsum, 2);
            lsum += __shfl_xor(lsum, 4);
            if (part == 0) {
                float al = __expf(mold - mtot);
                alpha_s[row] = al;
                lstat[row]   = lstat[row] * al + lsum;
                mstat[row]   = mtot;
            }
        }
        __syncthreads();

        // ---- PV: wave w owns channels w*64 .. w*64+63 (4 c-tiles) ----
        {
            float al[2][4];
            #pragma unroll
            for (int it = 0; it < 2; it++)
                #pragma unroll
                for (int r = 0; r < 4; r++) al[it][r] = alpha_s[it * 16 + quad * 4 + r];
            #pragma unroll
            for (int it = 0; it < 2; it++)
                #pragma unroll
                for (int ct = 0; ct < 4; ct++)
                    #pragma unroll
                    for (int r = 0; r < 4; r++) O[it][ct][r] *= al[it][r];

            #pragma unroll
            for (int ko = 0; ko < 2; ko++) {
                short8 pf[2];   // A[m=i][k=j] = P[i][j]
                #pragma unroll
                for (int it = 0; it < 2; it++)
                    pf[it] = *(const short8*)&psb[it * 16 + m16][ko * 32 + quad * 8];
                #pragma unroll
                for (int ct = 0; ct < 4; ct++) {
                    // B[k=j][n=c] = vT[c][j], 16B contiguous in j
                    short8 vf = *(const short8*)(vbase + (size_t)(ct * 16 + m16) * N_ + j0 + ko * 32 + quad * 8);
                    #pragma unroll
                    for (int it = 0; it < 2; it++)
                        O[it][ct] = __builtin_amdgcn_mfma_f32_16x16x32_bf16(pf[it], vf, O[it][ct], 0, 0, 0);
                }
            }
        }
        // no barrier needed here: next iteration's first barrier orders
        // psb/alpha reads (this iter) vs softmax writes (next iter); QK only
        // touches ps, which this iter's softmax already finished reading.
    }
    __syncthreads();

    // ---- epilogue: out[b][c][i] = gamma/l * O + x ----
    const float gmm = gamma_p[0];
    float scl[2][4];
    #pragma unroll
    for (int it = 0; it < 2; it++)
        #pragma unroll
        for (int r = 0; r < 4; r++) scl[it][r] = gmm / lstat[it * 16 + quad * 4 + r];

    #pragma unroll
    for (int it = 0; it < 2; it++)
        #pragma unroll
        for (int ct = 0; ct < 4; ct++) {
            size_t off = ((size_t)b * C_ + w * 64 + ct * 16 + m16) * N_ + i0 + it * 16 + quad * 4;
            f32x4 xv = *(const f32x4*)(x + off);
            f32x4 ov;
            #pragma unroll
            for (int r = 0; r < 4; r++) ov[r] = O[it][ct][r] * scl[it][r] + xv[r];
            *(f32x4*)(out + off) = ov;
        }
}

extern "C" void kernel_launch(void* const* d_in, const int* in_sizes, int n_in,
                              void* d_out, int out_size, void* d_ws, size_t ws_size,
                              hipStream_t stream)
{
    const float* x  = (const float*)d_in[0];
    const float* Wq = (const float*)d_in[1];
    const float* bq = (const float*)d_in[2];
    const float* Wk = (const float*)d_in[3];
    const float* bk = (const float*)d_in[4];
    const float* Wv = (const float*)d_in[5];
    const float* bv = (const float*)d_in[6];
    const float* gm = (const float*)d_in[7];
    float* out = (float*)d_out;

    ushort* qb = (ushort*)d_ws;                      // [B][N][CI] bf16  3.2 MB
    ushort* kb = qb + (size_t)B_ * N_ * CI_;         // [B][N][CI] bf16  3.2 MB
    ushort* vt = kb + (size_t)B_ * N_ * CI_;         // [B][C][N]  bf16 12.8 MB

    hipLaunchKernelGGL(proj_kernel, dim3(B_ * (N_ / PT)), dim3(256), 0, stream,
                       x, Wq, bq, Wk, bk, Wv, bv, qb, kb, vt);
    hipLaunchKernelGGL(attn_kernel, dim3(B_ * (N_ / TQ)), dim3(256), 0, stream,
                       qb, kb, vt, x, gm, out);
}

// Round 4
// 338.083 us; speedup vs baseline: 4.7757x; 1.7528x over previous
//
#include <hip/hip_runtime.h>

// PixelPropagationModule  out = gamma * (softmax(qk^T) @ v^T)^T + x
// B=8, C=256, CI=64, N=3136 (56x56), fp32 in/out.
// R3 = R2 with xtrans store-loop fix (rep<8, was rep<16 overwriting next tile).
//   wconv: Wq/Wk -> wqk[128][256] bf16, Wv -> wv[256][256] bf16
//   xtrans: x[B][C][N] f32 -> xT[B][N][C] bf16 (LDS tile transpose)
//   proj: per 64-pixel tile: QK GEMM C[o][pix], V GEMM C[pix][o], MFMA bf16
//   attn: unchanged (bf16 MFMA flash attention)

constexpr int B_  = 8;
constexpr int C_  = 256;
constexpr int CI_ = 64;
constexpr int N_  = 3136;
constexpr int TQ  = 32;     // attn query tile
constexpr int TJ  = 64;     // attn key tile
constexpr int PN  = 64;     // proj pixel tile
constexpr int XSP = C_ + 8; // proj LDS row pitch

typedef __attribute__((ext_vector_type(8))) short short8;   // 8 bf16 (4 VGPR)
typedef __attribute__((ext_vector_type(4))) float f32x4;

static __device__ inline ushort f2b(float f) {               // fp32 -> bf16 (RNE)
    unsigned u = __float_as_uint(f);
    return (ushort)((u + 0x7fffu + ((u >> 16) & 1u)) >> 16);
}

__global__ __launch_bounds__(256)
void wconv_kernel(const float* __restrict__ Wq, const float* __restrict__ Wk,
                  const float* __restrict__ Wv,
                  ushort* __restrict__ wqk, ushort* __restrict__ wv)
{
    int i = blockIdx.x * 256 + threadIdx.x;          // grid covers 65536
    if (i < 16384)      wqk[i] = f2b(Wq[i]);
    else if (i < 32768) wqk[i] = f2b(Wk[i - 16384]);
    wv[i] = f2b(Wv[i]);
}

__global__ __launch_bounds__(256)
void xtrans_kernel(const float* __restrict__ x, ushort* __restrict__ xT)
{
    __shared__ float ts[64][65];
    const int bx = blockIdx.x;
    const int b  = bx / 196;
    const int rm = bx % 196;
    const int n0 = (rm >> 2) * 64;
    const int c0 = (rm & 3) * 64;
    const int tid = threadIdx.x;

    const float* src = x + ((size_t)b * C_ + c0) * N_ + n0;
    #pragma unroll
    for (int rep = 0; rep < 16; rep++) {             // 4096 floats
        int e = rep * 256 + tid;
        int c = e >> 6, n = e & 63;
        ts[c][n] = src[(size_t)c * N_ + n];
    }
    __syncthreads();
    ushort* dst = xT + ((size_t)b * N_ + n0) * C_ + c0;
    #pragma unroll
    for (int rep = 0; rep < 8; rep++) {              // 2048 ushort2 = 4096 elems
        int e = rep * 256 + tid;
        int n = e >> 5, c2 = (e & 31) * 2;
        ushort2 o;
        o.x = f2b(ts[c2][n]);
        o.y = f2b(ts[c2 + 1][n]);
        *(ushort2*)(dst + (size_t)n * C_ + c2) = o;
    }
}

__global__ __launch_bounds__(256)
void proj_kernel(const ushort* __restrict__ xT, const ushort* __restrict__ wqk,
                 const ushort* __restrict__ wv,
                 const float* __restrict__ bq, const float* __restrict__ bk,
                 const float* __restrict__ bv,
                 ushort* __restrict__ qb, ushort* __restrict__ kb, ushort* __restrict__ vt)
{
    __shared__ ushort xs[PN][XSP];        // 33792 B
    const int b   = blockIdx.x / 49;
    const int n0  = (blockIdx.x % 49) * PN;
    const int tid = threadIdx.x;
    const int w    = tid >> 6;
    const int lane = tid & 63;
    const int m16  = lane & 15;
    const int quad = lane >> 4;

    // stage xT tile [64 pixels][256 c] bf16
    {
        const ushort* src = xT + ((size_t)b * N_ + n0) * C_;
        #pragma unroll
        for (int rep = 0; rep < 8; rep++) {
            int e = rep * 256 + tid;
            int row = e >> 5, ch = (e & 31) * 8;
            *(short8*)&xs[row][ch] = *(const short8*)(src + (size_t)row * C_ + ch);
        }
    }
    __syncthreads();

    // ---- QK GEMM: C[o][pixel]; waves 0,1 -> Q halves, 2,3 -> K halves ----
    {
        f32x4 acc[2][4];
        #pragma unroll
        for (int mt = 0; mt < 2; mt++)
            #pragma unroll
            for (int nt = 0; nt < 4; nt++) acc[mt][nt] = (f32x4){0.f, 0.f, 0.f, 0.f};

        #pragma unroll
        for (int kk = 0; kk < 8; kk++) {
            short8 af[2];
            #pragma unroll
            for (int mt = 0; mt < 2; mt++)   // A[m=o][k=c] = wqk row (L2-hot)
                af[mt] = *(const short8*)(wqk + (size_t)(w * 32 + mt * 16 + m16) * C_ + kk * 32 + quad * 8);
            #pragma unroll
            for (int nt = 0; nt < 4; nt++) {
                short8 bf = *(const short8*)&xs[nt * 16 + m16][kk * 32 + quad * 8];  // B[k=c][n=pix]
                #pragma unroll
                for (int mt = 0; mt < 2; mt++)
                    acc[mt][nt] = __builtin_amdgcn_mfma_f32_16x16x32_bf16(af[mt], bf, acc[mt][nt], 0, 0, 0);
            }
        }
        const float* bias = (w < 2) ? bq : bk;
        ushort* dst = (w < 2) ? qb : kb;
        const int obase = (w & 1) * 32;
        #pragma unroll
        for (int mt = 0; mt < 2; mt++) {
            f32x4 bs = *(const f32x4*)(bias + obase + mt * 16 + quad * 4);
            #pragma unroll
            for (int nt = 0; nt < 4; nt++) {
                ushort4 pk;
                pk.x = f2b(acc[mt][nt][0] + bs[0]);
                pk.y = f2b(acc[mt][nt][1] + bs[1]);
                pk.z = f2b(acc[mt][nt][2] + bs[2]);
                pk.w = f2b(acc[mt][nt][3] + bs[3]);
                *(ushort4*)(dst + ((size_t)b * N_ + n0 + nt * 16 + m16) * CI_ + obase + mt * 16 + quad * 4) = pk;
            }
        }
    }

    // ---- V GEMM: C[pixel][o]; wave w -> channels w*64..w*64+63 ----
    {
        f32x4 vacc[4][4];
        #pragma unroll
        for (int mt = 0; mt < 4; mt++)
            #pragma unroll
            for (int nt = 0; nt < 4; nt++) vacc[mt][nt] = (f32x4){0.f, 0.f, 0.f, 0.f};

        #pragma unroll
        for (int kk = 0; kk < 8; kk++) {
            short8 af[4];
            #pragma unroll
            for (int mt = 0; mt < 4; mt++)   // A[m=pix][k=c] from LDS
                af[mt] = *(const short8*)&xs[mt * 16 + m16][kk * 32 + quad * 8];
            #pragma unroll
            for (int nt = 0; nt < 4; nt++) {
                // B[k=c][n=o] = Wv[o][c], contiguous in c (L2-hot)
                short8 bf = *(const short8*)(wv + (size_t)(w * 64 + nt * 16 + m16) * C_ + kk * 32 + quad * 8);
                #pragma unroll
                for (int mt = 0; mt < 4; mt++)
                    vacc[mt][nt] = __builtin_amdgcn_mfma_f32_16x16x32_bf16(af[mt], bf, vacc[mt][nt], 0, 0, 0);
            }
        }
        #pragma unroll
        for (int nt = 0; nt < 4; nt++) {
            int c = w * 64 + nt * 16 + m16;
            float bvc = bv[c];
            #pragma unroll
            for (int mt = 0; mt < 4; mt++) {
                ushort4 pk;
                pk.x = f2b(vacc[mt][nt][0] + bvc);
                pk.y = f2b(vacc[mt][nt][1] + bvc);
                pk.z = f2b(vacc[mt][nt][2] + bvc);
                pk.w = f2b(vacc[mt][nt][3] + bvc);
                *(ushort4*)(vt + ((size_t)b * C_ + c) * N_ + n0 + mt * 16 + quad * 4) = pk;
            }
        }
    }
}

__global__ __launch_bounds__(256)
void attn_kernel(const ushort* __restrict__ qb, const ushort* __restrict__ kb,
                 const ushort* __restrict__ vt, const float* __restrict__ x,
                 const float* __restrict__ gamma_p, float* __restrict__ out)
{
    __shared__ float  ps[TQ][TJ + 4];
    __shared__ ushort psb[TQ][TJ + 8];
    __shared__ float  mstat[TQ], lstat[TQ], alpha_s[TQ];

    const int bpb  = N_ / TQ;             // 98 -> grid 784
    const int b    = blockIdx.x / bpb;
    const int i0   = (blockIdx.x % bpb) * TQ;
    const int tid  = threadIdx.x;
    const int w    = tid >> 6;
    const int lane = tid & 63;
    const int m16  = lane & 15;
    const int quad = lane >> 4;

    short8 qf[2][2];
    {
        const ushort* qbase = qb + ((size_t)b * N_ + i0) * CI_;
        #pragma unroll
        for (int it = 0; it < 2; it++)
            #pragma unroll
            for (int ko = 0; ko < 2; ko++)
                qf[it][ko] = *(const short8*)(qbase + (size_t)(it * 16 + m16) * CI_ + ko * 32 + quad * 8);
    }

    if (tid < TQ) { mstat[tid] = -3.0e38f; lstat[tid] = 0.f; }

    f32x4 O[2][4];
    #pragma unroll
    for (int it = 0; it < 2; it++)
        #pragma unroll
        for (int ct = 0; ct < 4; ct++) O[it][ct] = (f32x4){0.f, 0.f, 0.f, 0.f};

    const ushort* kbbase = kb + (size_t)b * N_ * CI_;
    const ushort* vbase  = vt + ((size_t)b * C_ + w * 64) * N_;

    for (int j0 = 0; j0 < N_; j0 += TJ) {
        {
            short8 kf[2];
            #pragma unroll
            for (int ko = 0; ko < 2; ko++)
                kf[ko] = *(const short8*)(kbbase + (size_t)(j0 + w * 16 + m16) * CI_ + ko * 32 + quad * 8);
            #pragma unroll
            for (int it = 0; it < 2; it++) {
                f32x4 s = (f32x4){0.f, 0.f, 0.f, 0.f};
                s = __builtin_amdgcn_mfma_f32_16x16x32_bf16(qf[it][0], kf[0], s, 0, 0, 0);
                s = __builtin_amdgcn_mfma_f32_16x16x32_bf16(qf[it][1], kf[1], s, 0, 0, 0);
                #pragma unroll
                for (int r = 0; r < 4; r++)
                    ps[it * 16 + quad * 4 + r][w * 16 + m16] = s[r];
            }
        }
        __syncthreads();

        {
            int row  = tid >> 3;
            int part = tid & 7;
            float* pr = &ps[row][part * 8];
            float mnew = -3.0e38f;
            #pragma unroll
            for (int u = 0; u < 8; u++) mnew = fmaxf(mnew, pr[u]);
            mnew = fmaxf(mnew, __shfl_xor(mnew, 1));
            mnew = fmaxf(mnew, __shfl_xor(mnew, 2));
            mnew = fmaxf(mnew, __shfl_xor(mnew, 4));
            float mold = mstat[row];
            float mtot = fmaxf(mold, mnew);
            float lsum = 0.f;
            ushort* pb = &psb[row][part * 8];
            #pragma unroll
            for (int u = 0; u < 8; u++) {
                float p = __expf(pr[u] - mtot);
                pb[u] = f2b(p);
                lsum += p;
            }
            lsum += __shfl_xor(lsum, 1);
            lsum += __shfl_xor(lsum, 2);
            lsum += __shfl_xor(lsum, 4);
            if (part == 0) {
                float al = __expf(mold - mtot);
                alpha_s[row] = al;
                lstat[row]   = lstat[row] * al + lsum;
                mstat[row]   = mtot;
            }
        }
        __syncthreads();

        {
            float al[2][4];
            #pragma unroll
            for (int it = 0; it < 2; it++)
                #pragma unroll
                for (int r = 0; r < 4; r++) al[it][r] = alpha_s[it * 16 + quad * 4 + r];
            #pragma unroll
            for (int it = 0; it < 2; it++)
                #pragma unroll
                for (int ct = 0; ct < 4; ct++)
                    #pragma unroll
                    for (int r = 0; r < 4; r++) O[it][ct][r] *= al[it][r];

            #pragma unroll
            for (int ko = 0; ko < 2; ko++) {
                short8 pf[2];
                #pragma unroll
                for (int it = 0; it < 2; it++)
                    pf[it] = *(const short8*)&psb[it * 16 + m16][ko * 32 + quad * 8];
                #pragma unroll
                for (int ct = 0; ct < 4; ct++) {
                    short8 vf = *(const short8*)(vbase + (size_t)(ct * 16 + m16) * N_ + j0 + ko * 32 + quad * 8);
                    #pragma unroll
                    for (int it = 0; it < 2; it++)
                        O[it][ct] = __builtin_amdgcn_mfma_f32_16x16x32_bf16(pf[it], vf, O[it][ct], 0, 0, 0);
                }
            }
        }
    }
    __syncthreads();

    const float gmm = gamma_p[0];
    float scl[2][4];
    #pragma unroll
    for (int it = 0; it < 2; it++)
        #pragma unroll
        for (int r = 0; r < 4; r++) scl[it][r] = gmm / lstat[it * 16 + quad * 4 + r];

    #pragma unroll
    for (int it = 0; it < 2; it++)
        #pragma unroll
        for (int ct = 0; ct < 4; ct++) {
            size_t off = ((size_t)b * C_ + w * 64 + ct * 16 + m16) * N_ + i0 + it * 16 + quad * 4;
            f32x4 xv = *(const f32x4*)(x + off);
            f32x4 ov;
            #pragma unroll
            for (int r = 0; r < 4; r++) ov[r] = O[it][ct][r] * scl[it][r] + xv[r];
            *(f32x4*)(out + off) = ov;
        }
}

extern "C" void kernel_launch(void* const* d_in, const int* in_sizes, int n_in,
                              void* d_out, int out_size, void* d_ws, size_t ws_size,
                              hipStream_t stream)
{
    const float* x  = (const float*)d_in[0];
    const float* Wq = (const float*)d_in[1];
    const float* bq = (const float*)d_in[2];
    const float* Wk = (const float*)d_in[3];
    const float* bk = (const float*)d_in[4];
    const float* Wv = (const float*)d_in[5];
    const float* bv = (const float*)d_in[6];
    const float* gm = (const float*)d_in[7];
    float* out = (float*)d_out;

    ushort* qb   = (ushort*)d_ws;                    // [B][N][CI]  3.2 MB
    ushort* kb   = qb + (size_t)B_ * N_ * CI_;       // [B][N][CI]  3.2 MB
    ushort* vt   = kb + (size_t)B_ * N_ * CI_;       // [B][C][N]  12.8 MB
    ushort* xT   = vt + (size_t)B_ * C_ * N_;        // [B][N][C]  12.8 MB
    ushort* wqk  = xT + (size_t)B_ * N_ * C_;        // [128][256] 64 KB
    ushort* wv   = wqk + 128 * C_;                   // [256][256] 128 KB

    hipLaunchKernelGGL(wconv_kernel, dim3(256), dim3(256), 0, stream, Wq, Wk, Wv, wqk, wv);
    hipLaunchKernelGGL(xtrans_kernel, dim3(B_ * 196), dim3(256), 0, stream, x, xT);
    hipLaunchKernelGGL(proj_kernel, dim3(B_ * 49), dim3(256), 0, stream,
                       xT, wqk, wv, bq, bk, bv, qb, kb, vt);
    hipLaunchKernelGGL(attn_kernel, dim3(B_ * (N_ / TQ)), dim3(256), 0, stream,
                       qb, kb, vt, x, gm, out);
}